// Round 8
// baseline (835.628 us; speedup 1.0000x reference)
//
#include <hip/hip_runtime.h>
#include <math.h>

#define N_NODES 50000
#define N_EDGES 600000
#define N_GRAPHS 512
#define F_IN 128
#define D_HID 128
#define EDIM 384
#define M_ALL (N_NODES + N_GRAPHS)  // node rows + appended pooled graph rows

typedef __attribute__((ext_vector_type(8))) short bf16x8;
typedef __attribute__((ext_vector_type(4))) float f32x4;
typedef __attribute__((ext_vector_type(16))) float f32x16;

static __device__ __forceinline__ float wave_reduce_sum(float s) {
#pragma unroll
  for (int off = 32; off > 0; off >>= 1) s += __shfl_xor(s, off, 64);
  return s;
}

static __device__ __forceinline__ int wave_reduce_sum_i(int s) {
#pragma unroll
  for (int off = 32; off > 0; off >>= 1) s += __shfl_xor(s, off, 64);
  return s;
}

static __device__ __forceinline__ short f2b(float f) {
  unsigned u = __float_as_uint(f);
  unsigned r = (u + 0x7FFFu + ((u >> 16) & 1u)) >> 16;
  return (short)r;
}

static __device__ __forceinline__ float b2f(short s) {
  return __uint_as_float(((unsigned)(unsigned short)s) << 16);
}

// ---------------- graph preprocessing ----------------

#define SCAN_BS 256
#define SCAN_NB ((N_NODES + SCAN_BS - 1) / SCAN_BS)  // 196

// zero cnt + compute gptr (binary search over sorted batch), one launch
__global__ __launch_bounds__(SCAN_BS) void init_kernel(const int* __restrict__ batch,
                                                       int* __restrict__ cnt,
                                                       int* __restrict__ gptr) {
  int i = blockIdx.x * SCAN_BS + threadIdx.x;
  if (i < N_NODES) cnt[i] = 0;
  if (i <= N_GRAPHS) {
    int lo = 0, hi = N_NODES;
    while (lo < hi) { int mid = (lo + hi) >> 1; if (batch[mid] < i) lo = mid + 1; else hi = mid; }
    gptr[i] = lo;
  }
}

__global__ void hist_kernel(const int* __restrict__ dst, int* __restrict__ cnt) {
  int i = blockIdx.x * blockDim.x + threadIdx.x;
  if (i < N_EDGES) atomicAdd(&cnt[dst[i]], 1);
}

__global__ __launch_bounds__(SCAN_BS) void scan1_kernel(const int* __restrict__ cnt,
                                                        int* __restrict__ row_ptr,
                                                        int* __restrict__ bsum) {
  __shared__ int wsum[4];
  int tid = threadIdx.x, lane = tid & 63, wid = tid >> 6;
  int idx = blockIdx.x * SCAN_BS + tid;
  int v = (idx < N_NODES) ? cnt[idx] : 0;
  int x = v;
#pragma unroll
  for (int off = 1; off < 64; off <<= 1) {
    int t = __shfl_up(x, off, 64);
    if (lane >= off) x += t;
  }
  if (lane == 63) wsum[wid] = x;
  __syncthreads();
  int pre = 0, tot = 0;
#pragma unroll
  for (int w = 0; w < 4; ++w) { int s = wsum[w]; tot += s; if (w < wid) pre += s; }
  if (idx < N_NODES) row_ptr[idx + 1] = x + pre;  // block-local inclusive
  if (tid == 0) bsum[blockIdx.x] = tot;
}

// scan3 with fused scan2 (local re-reduction of bsum prefix) + fused dinv
__global__ __launch_bounds__(SCAN_BS) void scan3_kernel(const int* __restrict__ cnt,
                                                        const int* __restrict__ bsum,
                                                        int* __restrict__ row_ptr,
                                                        int* __restrict__ cursor,
                                                        float* __restrict__ dinv) {
  __shared__ int ws[4];
  int tid = threadIdx.x, lane = tid & 63, wid = tid >> 6;
  int v = 0;
  if (tid < SCAN_NB && tid < blockIdx.x) v = bsum[tid];
  v = wave_reduce_sum_i(v);
  if (lane == 0) ws[wid] = v;
  __syncthreads();
  int boff = ws[0] + ws[1] + ws[2] + ws[3];
  int idx = blockIdx.x * SCAN_BS + tid;
  if (idx >= N_NODES) return;
  int val = row_ptr[idx + 1] + boff;
  row_ptr[idx + 1] = val;
  int c = cnt[idx];
  cursor[idx] = val - c;
  dinv[idx] = 1.0f / sqrtf((float)(c + 1));
  if (idx == 0) row_ptr[0] = 0;
}

__global__ void scatter_kernel(const int* __restrict__ src, const int* __restrict__ dst,
                               const float* __restrict__ dinv, int* __restrict__ cursor,
                               int* __restrict__ col, float* __restrict__ ew) {
  int e = blockIdx.x * blockDim.x + threadIdx.x;
  if (e >= N_EDGES) return;
  int s = src[e], d = dst[e];
  int pos = atomicAdd(&cursor[d], 1);
  col[pos] = s;
  ew[pos] = dinv[s] * dinv[d];
}

// ---------------- combined weight convert+transpose (10 matrices, 1 launch) ----

struct WcSeg { const float* W; short* Wt; int K; int Nc; };
struct WcArgs { WcSeg seg[10]; };

__global__ void wconv_all_kernel(WcArgs a) {
  int sidx = blockIdx.y;
  WcSeg s = a.seg[sidx];
  int i = blockIdx.x * blockDim.x + threadIdx.x;
  if (i >= s.K * s.Nc) return;
  int k = i / s.Nc, n = i - k * s.Nc;
  s.Wt[(size_t)n * s.K + k] = f2b(s.W[i]);
}

// ---------------- logmap0 for BOTH branches -> interleaved Ab[node][f:128|s:128] ----

__global__ __launch_bounds__(256) void logmap2_kernel(const float* __restrict__ x,
                                                      const float* __restrict__ x_s,
                                                      short* __restrict__ Ab) {
  int w = blockIdx.x * 4 + (threadIdx.x >> 6);
  int lane = threadIdx.x & 63;
  if (w >= 2 * N_NODES) return;
  int br = (w >= N_NODES) ? 1 : 0;
  int row = br ? (w - N_NODES) : w;
  const float* xr = (br ? x_s : x) + (size_t)row * F_IN;
  float2 v = *(const float2*)(xr + lane * 2);
  float s = wave_reduce_sum(v.x * v.x + v.y * v.y);
  float n = sqrtf(s);
  float nc = fmaxf(n, 1e-15f);
  float f = atanhf(fminf(nc, 0.9999999f)) / nc;
  short2 o; o.x = f2b(v.x * f); o.y = f2b(v.y * f);
  *(short2*)(Ab + (size_t)row * 256 + br * 128 + lane * 2) = o;
}

// ---------------- CSR aggregation, both branches per gather (512B rows) ----------

__global__ __launch_bounds__(256) void agg2_kernel(const short* __restrict__ Xin, int lda,
                                                   const float* __restrict__ dinv,
                                                   const int* __restrict__ row_ptr,
                                                   const int* __restrict__ col,
                                                   const float* __restrict__ ew,
                                                   short* __restrict__ Xa) {
  int node = blockIdx.x * 4 + (threadIdx.x >> 6);
  int lane = threadIdx.x & 63;
  if (node >= N_NODES) return;
  float di = dinv[node];
  float wsf = di * di;
  short4 sv = *(const short4*)(Xin + (size_t)node * lda + lane * 4);
  float a0 = b2f(sv.x) * wsf, a1 = b2f(sv.y) * wsf, a2 = b2f(sv.z) * wsf, a3 = b2f(sv.w) * wsf;
  int s = row_ptr[node], e = row_ptr[node + 1];
  int j = s;
  for (; j + 4 <= e; j += 4) {
    int c0 = col[j], c1 = col[j + 1], c2 = col[j + 2], c3 = col[j + 3];
    float w0 = ew[j], w1 = ew[j + 1], w2 = ew[j + 2], w3 = ew[j + 3];
    short4 v0 = *(const short4*)(Xin + (size_t)c0 * lda + lane * 4);
    short4 v1 = *(const short4*)(Xin + (size_t)c1 * lda + lane * 4);
    short4 v2 = *(const short4*)(Xin + (size_t)c2 * lda + lane * 4);
    short4 v3 = *(const short4*)(Xin + (size_t)c3 * lda + lane * 4);
    a0 += b2f(v0.x) * w0; a1 += b2f(v0.y) * w0; a2 += b2f(v0.z) * w0; a3 += b2f(v0.w) * w0;
    a0 += b2f(v1.x) * w1; a1 += b2f(v1.y) * w1; a2 += b2f(v1.z) * w1; a3 += b2f(v1.w) * w1;
    a0 += b2f(v2.x) * w2; a1 += b2f(v2.y) * w2; a2 += b2f(v2.z) * w2; a3 += b2f(v2.w) * w2;
    a0 += b2f(v3.x) * w3; a1 += b2f(v3.y) * w3; a2 += b2f(v3.z) * w3; a3 += b2f(v3.w) * w3;
  }
  for (; j < e; ++j) {
    float w0 = ew[j];
    short4 v0 = *(const short4*)(Xin + (size_t)col[j] * lda + lane * 4);
    a0 += b2f(v0.x) * w0; a1 += b2f(v0.y) * w0; a2 += b2f(v0.z) * w0; a3 += b2f(v0.w) * w0;
  }
  short4 o; o.x = f2b(a0); o.y = f2b(a1); o.z = f2b(a2); o.w = f2b(a3);
  *(short4*)(Xa + (size_t)node * 256 + lane * 4) = o;
}

// ---------------- bf16 MFMA GEMM, z-batched (2 independent problems) ----------

#define LDK 40  // 32 + 8 pad shorts

struct GemmZArgs {
  const short* A[2];
  const short* Bt[2];
  const float* bias[2];
  short* Cb[2];
  int lda, ldc, M, Nc, K, kexp, do_relu;
};

__global__ __launch_bounds__(256) void mfma_gemmz_kernel(GemmZArgs g) {
  __shared__ __align__(16) short As[128 * LDK];
  __shared__ __align__(16) short Bs[128 * LDK];
  int z = blockIdx.z;
  const short* __restrict__ A = g.A[z];
  const short* __restrict__ Bt = g.Bt[z];
  int tid = threadIdx.x;
  int wave = tid >> 6, lane = tid & 63;
  int wr = (wave >> 1) * 64, wc = (wave & 1) * 64;
  int q = lane >> 4, m = lane & 15;
  int row0 = blockIdx.x * 128, col0 = blockIdx.y * 128;
  f32x4 acc[4][4] = {};
  for (int k0 = 0; k0 < g.K; k0 += 32) {
#pragma unroll
    for (int p = 0; p < 2; ++p) {
      int idx = p * 256 + tid;      // 0..511
      int r = idx >> 2, kc = (idx & 3) * 8;
      int gr = row0 + r;
      int kk = k0 + kc;
      int acol = g.kexp ? (kk + ((kk >> 7) << 7)) : kk;
      float4 v = make_float4(0.f, 0.f, 0.f, 0.f);
      if (gr < g.M) v = *(const float4*)(A + (size_t)gr * g.lda + acol);
      *(float4*)(As + r * LDK + kc) = v;
      float4 w = *(const float4*)(Bt + (size_t)(col0 + r) * g.K + kk);
      *(float4*)(Bs + r * LDK + kc) = w;
    }
    __syncthreads();
    bf16x8 af[4], bfr[4];
#pragma unroll
    for (int i = 0; i < 4; ++i) {
      af[i]  = *(const bf16x8*)(As + (wr + i * 16 + m) * LDK + q * 8);
      bfr[i] = *(const bf16x8*)(Bs + (wc + i * 16 + m) * LDK + q * 8);
    }
#pragma unroll
    for (int i = 0; i < 4; ++i)
#pragma unroll
      for (int j = 0; j < 4; ++j)
        acc[i][j] = __builtin_amdgcn_mfma_f32_16x16x32_bf16(af[i], bfr[j], acc[i][j], 0, 0, 0);
    __syncthreads();
  }
  const float* __restrict__ bias = g.bias[z];
  short* __restrict__ Cb = g.Cb[z];
#pragma unroll
  for (int i = 0; i < 4; ++i) {
#pragma unroll
    for (int r = 0; r < 4; ++r) {
      int rr = row0 + wr + i * 16 + q * 4 + r;
      if (rr >= g.M) continue;
#pragma unroll
      for (int j = 0; j < 4; ++j) {
        int cc = col0 + wc + j * 16 + m;
        float v = acc[i][j][r];
        if (bias) v += bias[cc];
        if (g.do_relu) v = fmaxf(v, 0.0f);
        Cb[(size_t)rr * g.ldc + cc] = f2b(v);
      }
    }
  }
}

// ---------------- fused 2-layer MLP head + expmap0/proj, LDS-free GEMM loops ----
// out = expproj( relu(A @ B1^T) @ B2^T ), per block: 128 rows x full 384x384.
// 512 thr, 8 waves; wave = 64 rows (2 x 32-row frags) x 96 cols (3 x 32-col
// frags), 32x32x16 MFMA, acc f32x16. Operands read DIRECTLY from global
// (B1/B2 are L2-resident, shared by all blocks); no As/Bs LDS, no barriers in
// the K loops. Only the hidden matrix H (bf16, 128x392) lives in LDS (one
// barrier). 32x32x16 layouts: A row=lane&31, k=(lane>>5)*8+e; B col=lane&31,
// same k; C/D col=lane&31, row=(reg&3)+8*(reg>>2)+4*(lane>>5).
// Extra blocks (x >= gx_h, z==0) run the g-head problem p[2].

#define HLD 392  // 384 + 8 pad shorts; row stride 49 x 16B (odd) -> conflict-free

struct MlpProb {
  const short* A;
  const short* B1;     // [384][K1]
  const short* B2;     // [384][384]
  float* Cf;
  float* Cf2;
  int lda, M, K1, kexp, split;
};
struct Mlp2Args { MlpProb p[3]; int gx_h; };

__global__ __launch_bounds__(512) void mlp2_kernel(Mlp2Args g) {
  __shared__ __align__(16) short H[128 * HLD];
  __shared__ float nsum[128][4];
  int z = blockIdx.z;
  int bx = blockIdx.x;
  MlpProb p;
  int row0;
  if (bx < g.gx_h) { p = g.p[z]; row0 = bx * 128; }
  else { if (z) return; p = g.p[2]; row0 = (bx - g.gx_h) * 128; }

  int tid = threadIdx.x;
  int wave = tid >> 6, lane = tid & 63;
  int l31 = lane & 31, lh = lane >> 5;
  int rg = wave & 1;   // row group: rows rg*64..+63
  int cq = wave >> 1;  // col quarter: cols cq*96..+95

  const short* Arow0 = p.A + (size_t)(row0 + rg * 64 + l31) * p.lda;
  const short* Arow1 = Arow0 + (size_t)32 * p.lda;
  const short* B1c0 = p.B1 + (size_t)(cq * 96 + l31) * p.K1;
  const short* B1c1 = B1c0 + (size_t)32 * p.K1;
  const short* B1c2 = B1c1 + (size_t)32 * p.K1;

  f32x16 acc0[2][3] = {};
  // ---- stage 1: hidden = relu(A @ B1^T), no LDS, no barriers ----
#pragma unroll 2
  for (int k0 = 0; k0 < p.K1; k0 += 16) {
    int kk = k0 + lh * 8;
    int acol = p.kexp ? (kk + ((kk >> 7) << 7)) : kk;
    bf16x8 a0 = *(const bf16x8*)(Arow0 + acol);
    bf16x8 a1 = *(const bf16x8*)(Arow1 + acol);
    bf16x8 b0 = *(const bf16x8*)(B1c0 + kk);
    bf16x8 b1 = *(const bf16x8*)(B1c1 + kk);
    bf16x8 b2 = *(const bf16x8*)(B1c2 + kk);
    acc0[0][0] = __builtin_amdgcn_mfma_f32_32x32x16_bf16(a0, b0, acc0[0][0], 0, 0, 0);
    acc0[1][0] = __builtin_amdgcn_mfma_f32_32x32x16_bf16(a1, b0, acc0[1][0], 0, 0, 0);
    acc0[0][1] = __builtin_amdgcn_mfma_f32_32x32x16_bf16(a0, b1, acc0[0][1], 0, 0, 0);
    acc0[1][1] = __builtin_amdgcn_mfma_f32_32x32x16_bf16(a1, b1, acc0[1][1], 0, 0, 0);
    acc0[0][2] = __builtin_amdgcn_mfma_f32_32x32x16_bf16(a0, b2, acc0[0][2], 0, 0, 0);
    acc0[1][2] = __builtin_amdgcn_mfma_f32_32x32x16_bf16(a1, b2, acc0[1][2], 0, 0, 0);
  }
  // ---- relu + bf16 hidden -> LDS H ----
#pragma unroll
  for (int rf = 0; rf < 2; ++rf)
#pragma unroll
    for (int f = 0; f < 3; ++f)
#pragma unroll
      for (int reg = 0; reg < 16; ++reg) {
        int rl = rg * 64 + rf * 32 + (reg & 3) + 8 * (reg >> 2) + 4 * lh;
        H[rl * HLD + cq * 96 + f * 32 + l31] = f2b(fmaxf(acc0[rf][f][reg], 0.0f));
      }
  __syncthreads();
  // ---- stage 2: out = H @ B2^T; A from LDS (conflict-free), B from global ----
  const short* B2c0 = p.B2 + (size_t)(cq * 96 + l31) * 384;
  const short* B2c1 = B2c0 + (size_t)32 * 384;
  const short* B2c2 = B2c1 + (size_t)32 * 384;
  const short* H0 = H + (rg * 64 + l31) * HLD;
  const short* H1 = H0 + 32 * HLD;
  f32x16 acc[2][3] = {};
#pragma unroll 2
  for (int k0 = 0; k0 < 384; k0 += 16) {
    int kk = k0 + lh * 8;
    bf16x8 a0 = *(const bf16x8*)(H0 + kk);
    bf16x8 a1 = *(const bf16x8*)(H1 + kk);
    bf16x8 b0 = *(const bf16x8*)(B2c0 + kk);
    bf16x8 b1 = *(const bf16x8*)(B2c1 + kk);
    bf16x8 b2 = *(const bf16x8*)(B2c2 + kk);
    acc[0][0] = __builtin_amdgcn_mfma_f32_32x32x16_bf16(a0, b0, acc[0][0], 0, 0, 0);
    acc[1][0] = __builtin_amdgcn_mfma_f32_32x32x16_bf16(a1, b0, acc[1][0], 0, 0, 0);
    acc[0][1] = __builtin_amdgcn_mfma_f32_32x32x16_bf16(a0, b1, acc[0][1], 0, 0, 0);
    acc[1][1] = __builtin_amdgcn_mfma_f32_32x32x16_bf16(a1, b1, acc[1][1], 0, 0, 0);
    acc[0][2] = __builtin_amdgcn_mfma_f32_32x32x16_bf16(a0, b2, acc[0][2], 0, 0, 0);
    acc[1][2] = __builtin_amdgcn_mfma_f32_32x32x16_bf16(a1, b2, acc[1][2], 0, 0, 0);
  }
  // ---- per-row norm partials (this wave's 96-col quarter) ----
#pragma unroll
  for (int rf = 0; rf < 2; ++rf)
#pragma unroll
    for (int reg = 0; reg < 16; ++reg) {
      float s = acc[rf][0][reg] * acc[rf][0][reg] + acc[rf][1][reg] * acc[rf][1][reg] +
                acc[rf][2][reg] * acc[rf][2][reg];
      s += __shfl_xor(s, 1, 64);
      s += __shfl_xor(s, 2, 64);
      s += __shfl_xor(s, 4, 64);
      s += __shfl_xor(s, 8, 64);
      s += __shfl_xor(s, 16, 64);
      if (l31 == 0)
        nsum[rg * 64 + rf * 32 + (reg & 3) + 8 * (reg >> 2) + 4 * lh][cq] = s;
    }
  __syncthreads();
  // ---- expmap0 + proj + store ----
  const float maxn = 1.0f - 4e-3f;
#pragma unroll
  for (int rf = 0; rf < 2; ++rf)
#pragma unroll
    for (int reg = 0; reg < 16; ++reg) {
      int rl = rg * 64 + rf * 32 + (reg & 3) + 8 * (reg >> 2) + 4 * lh;
      int rr = row0 + rl;
      if (rr >= p.M) continue;
      float s = nsum[rl][0] + nsum[rl][1] + nsum[rl][2] + nsum[rl][3];
      float n = fmaxf(sqrtf(s), 1e-15f);
      float th = tanhf(n);
      float fct = th / n;
      float n2 = fmaxf(th, 1e-15f);
      if (n2 > maxn) fct *= maxn / n2;
      float* base = (rr < p.split) ? (p.Cf + (size_t)rr * 384)
                                   : (p.Cf2 + (size_t)(rr - p.split) * 384);
#pragma unroll
      for (int f = 0; f < 3; ++f)
        base[cq * 96 + f * 32 + l31] = acc[rf][f][reg] * fct;
    }
}

// ---------------- global_add_pool over sorted batch, interleaved layout ----------

__global__ __launch_bounds__(768) void pool2_kernel(const short* __restrict__ NB,
                                                    const int* __restrict__ gptr,
                                                    short* __restrict__ GCb,
                                                    short* __restrict__ nbappend) {
  int g = blockIdx.x, t = threadIdx.x;  // t in [0,768)
  int s = gptr[g], e = gptr[g + 1];
  float acc = 0.0f;
  for (int i = s; i < e; ++i) acc += b2f(NB[(size_t)i * 768 + t]);
  short bv = f2b(acc);
  int l = t >> 8, rem = t & 255, b = rem >> 7, c = rem & 127;
  GCb[(size_t)g * 768 + b * 384 + l * 128 + c] = bv;
  nbappend[(size_t)g * 768 + t] = bv;
}

// ---------------- driver ----------------

extern "C" void kernel_launch(void* const* d_in, const int* in_sizes, int n_in,
                              void* d_out, int out_size, void* d_ws, size_t ws_size,
                              hipStream_t stream) {
  (void)in_sizes; (void)n_in; (void)out_size; (void)ws_size;
  const float* x   = (const float*)d_in[0];
  const float* x_s = (const float*)d_in[1];
  const int* src   = (const int*)d_in[2];
  const int* dst   = (const int*)d_in[3];
  const int* batch = (const int*)d_in[4];
  const float* Wf[3] = {(const float*)d_in[5], (const float*)d_in[6], (const float*)d_in[7]};
  const float* bf[3] = {(const float*)d_in[8], (const float*)d_in[9], (const float*)d_in[10]};
  const float* Wsb[3] = {(const float*)d_in[11], (const float*)d_in[12], (const float*)d_in[13]};
  const float* bs[3] = {(const float*)d_in[14], (const float*)d_in[15], (const float*)d_in[16]};
  const float* P1 = (const float*)d_in[17];
  const float* P2 = (const float*)d_in[18];
  const float* G1 = (const float*)d_in[19];
  const float* G2 = (const float*)d_in[20];
  float* out = (float*)d_out;

  char* w = (char*)d_ws;
  auto alloc = [&](size_t bytes) {
    char* p = w;
    w += (bytes + 255) & ~(size_t)255;
    return p;
  };
  short* Ab    = (short*)alloc((size_t)N_NODES * 256 * 2);   // logmap out, interleaved
  short* Xa    = (short*)alloc((size_t)N_NODES * 256 * 2);   // aggregated, interleaved
  short* NB    = (short*)alloc((size_t)M_ALL * 768 * 2);     // [row][l][branch][128]
  int* cnt     = (int*)alloc((size_t)N_NODES * 4);
  int* row_ptr = (int*)alloc((size_t)(N_NODES + 1) * 4);
  int* cursor  = (int*)alloc((size_t)N_NODES * 4);
  float* dinv  = (float*)alloc((size_t)N_NODES * 4);
  int* col     = (int*)alloc((size_t)N_EDGES * 4);
  float* ew    = (float*)alloc((size_t)N_EDGES * 4);
  int* gptr    = (int*)alloc((size_t)(N_GRAPHS + 1) * 4);
  int* bsum    = (int*)alloc(256 * 4);
  short* GCb   = (short*)alloc((size_t)N_GRAPHS * 768 * 2);
  short* P1t   = (short*)alloc((size_t)EDIM * EDIM * 2);
  short* P2t   = (short*)alloc((size_t)EDIM * EDIM * 2);
  short* G1t   = (short*)alloc((size_t)768 * EDIM * 2);
  short* G2t   = (short*)alloc((size_t)EDIM * EDIM * 2);
  short* Wft[3], *Wst[3];
  for (int l = 0; l < 3; ++l) {
    Wft[l] = (short*)alloc((size_t)128 * 128 * 2);
    Wst[l] = (short*)alloc((size_t)128 * 128 * 2);
  }

  // ---- weight convert (independent of graph) ----
  {
    WcArgs wa;
    wa.seg[0] = {P1, P1t, EDIM, EDIM};
    wa.seg[1] = {P2, P2t, EDIM, EDIM};
    wa.seg[2] = {G1, G1t, 768, EDIM};
    wa.seg[3] = {G2, G2t, EDIM, EDIM};
    for (int l = 0; l < 3; ++l) {
      wa.seg[4 + l] = {Wf[l], Wft[l], 128, 128};
      wa.seg[7 + l] = {Wsb[l], Wst[l], 128, 128};
    }
    wconv_all_kernel<<<dim3((768 * EDIM + 255) / 256, 10), 256, 0, stream>>>(wa);
  }

  // ---- graph structure: 5 launches ----
  init_kernel<<<SCAN_NB, SCAN_BS, 0, stream>>>(batch, cnt, gptr);
  hist_kernel<<<(N_EDGES + 255) / 256, 256, 0, stream>>>(dst, cnt);
  scan1_kernel<<<SCAN_NB, SCAN_BS, 0, stream>>>(cnt, row_ptr, bsum);
  scan3_kernel<<<SCAN_NB, SCAN_BS, 0, stream>>>(cnt, bsum, row_ptr, cursor, dinv);
  scatter_kernel<<<(N_EDGES + 255) / 256, 256, 0, stream>>>(src, dst, dinv, cursor, col, ew);

  const size_t OUT0 = 0;
  const size_t OUT1 = (size_t)N_GRAPHS * EDIM;
  const size_t OUT2 = OUT1 + (size_t)N_GRAPHS * EDIM;
  const size_t OUT3 = OUT2 + (size_t)N_NODES * EDIM;

  const int gx_layer = (N_NODES + 127) / 128;   // 391
  const int gx_mfma  = (M_ALL + 127) / 128;     // 395
  const int gx_agg   = (N_NODES + 3) / 4;       // 12500

  // ---- logmap both branches -> interleaved Ab ----
  logmap2_kernel<<<(2 * N_NODES + 3) / 4, 256, 0, stream>>>(x, x_s, Ab);

  // ---- 3 GCN layers, both branches per launch ----
  const short* cur = Ab;
  int clda = 256;
  for (int l = 0; l < 3; ++l) {
    agg2_kernel<<<gx_agg, 256, 0, stream>>>(cur, clda, dinv, row_ptr, col, ew, Xa);
    GemmZArgs ga = {};
    ga.A[0] = Xa;        ga.A[1] = Xa + 128;
    ga.Bt[0] = Wft[l];   ga.Bt[1] = Wst[l];
    ga.bias[0] = bf[l];  ga.bias[1] = bs[l];
    ga.Cb[0] = NB + l * 256;        ga.Cb[1] = NB + l * 256 + 128;
    ga.lda = 256; ga.ldc = 768; ga.M = N_NODES; ga.Nc = 128; ga.K = 128;
    ga.kexp = 0; ga.do_relu = 1;
    mfma_gemmz_kernel<<<dim3(gx_layer, 1, 2), 256, 0, stream>>>(ga);
    cur = NB + l * 256;
    clda = 768;
  }

  // ---- pool (both branches) + append pooled rows to NB ----
  pool2_kernel<<<N_GRAPHS, 768, 0, stream>>>(NB, gptr, GCb, NB + (size_t)N_NODES * 768);

  // ---- all MLP heads in ONE dispatch: z=0/1 node+graph heads, tail-x = g head ----
  {
    const int gx_g = (N_GRAPHS + 127) / 128;  // 4
    Mlp2Args h = {};
    h.p[0] = {NB,       P1t, P2t, out + OUT2,
              out + OUT1, 768, M_ALL, EDIM, 1, N_NODES};
    h.p[1] = {NB + 128, P1t, P2t, out + OUT3 + (size_t)N_GRAPHS * EDIM,
              out + OUT3, 768, M_ALL, EDIM, 1, N_NODES};
    h.p[2] = {GCb, G1t, G2t, out + OUT0, out + OUT0, 768, N_GRAPHS, 768, 0, 1 << 30};
    h.gx_h = gx_mfma;
    mlp2_kernel<<<dim3(gx_mfma + gx_g, 1, 2), 512, 0, stream>>>(h);
  }
}

// Round 9
// 748.690 us; speedup vs baseline: 1.1161x; 1.1161x over previous
//
#include <hip/hip_runtime.h>
#include <math.h>

#define N_NODES 50000
#define N_EDGES 600000
#define N_GRAPHS 512
#define F_IN 128
#define D_HID 128
#define EDIM 384
#define M_ALL (N_NODES + N_GRAPHS)  // node rows + appended pooled graph rows

typedef __attribute__((ext_vector_type(8))) short bf16x8;
typedef __attribute__((ext_vector_type(4))) float f32x4;
typedef __attribute__((ext_vector_type(16))) float f32x16;

static __device__ __forceinline__ float wave_reduce_sum(float s) {
#pragma unroll
  for (int off = 32; off > 0; off >>= 1) s += __shfl_xor(s, off, 64);
  return s;
}

static __device__ __forceinline__ int wave_reduce_sum_i(int s) {
#pragma unroll
  for (int off = 32; off > 0; off >>= 1) s += __shfl_xor(s, off, 64);
  return s;
}

static __device__ __forceinline__ short f2b(float f) {
  unsigned u = __float_as_uint(f);
  unsigned r = (u + 0x7FFFu + ((u >> 16) & 1u)) >> 16;
  return (short)r;
}

static __device__ __forceinline__ float b2f(short s) {
  return __uint_as_float(((unsigned)(unsigned short)s) << 16);
}

// ---------------- graph preprocessing ----------------

#define SCAN_BS 256
#define SCAN_NB ((N_NODES + SCAN_BS - 1) / SCAN_BS)  // 196

// zero cnt + compute gptr (binary search over sorted batch), one launch
__global__ __launch_bounds__(SCAN_BS) void init_kernel(const int* __restrict__ batch,
                                                       int* __restrict__ cnt,
                                                       int* __restrict__ gptr) {
  int i = blockIdx.x * SCAN_BS + threadIdx.x;
  if (i < N_NODES) cnt[i] = 0;
  if (i <= N_GRAPHS) {
    int lo = 0, hi = N_NODES;
    while (lo < hi) { int mid = (lo + hi) >> 1; if (batch[mid] < i) lo = mid + 1; else hi = mid; }
    gptr[i] = lo;
  }
}

__global__ void hist_kernel(const int* __restrict__ dst, int* __restrict__ cnt) {
  int i = blockIdx.x * blockDim.x + threadIdx.x;
  if (i < N_EDGES) atomicAdd(&cnt[dst[i]], 1);
}

__global__ __launch_bounds__(SCAN_BS) void scan1_kernel(const int* __restrict__ cnt,
                                                        int* __restrict__ row_ptr,
                                                        int* __restrict__ bsum) {
  __shared__ int wsum[4];
  int tid = threadIdx.x, lane = tid & 63, wid = tid >> 6;
  int idx = blockIdx.x * SCAN_BS + tid;
  int v = (idx < N_NODES) ? cnt[idx] : 0;
  int x = v;
#pragma unroll
  for (int off = 1; off < 64; off <<= 1) {
    int t = __shfl_up(x, off, 64);
    if (lane >= off) x += t;
  }
  if (lane == 63) wsum[wid] = x;
  __syncthreads();
  int pre = 0, tot = 0;
#pragma unroll
  for (int w = 0; w < 4; ++w) { int s = wsum[w]; tot += s; if (w < wid) pre += s; }
  if (idx < N_NODES) row_ptr[idx + 1] = x + pre;  // block-local inclusive
  if (tid == 0) bsum[blockIdx.x] = tot;
}

// scan3 with fused scan2 (local re-reduction of bsum prefix) + fused dinv
__global__ __launch_bounds__(SCAN_BS) void scan3_kernel(const int* __restrict__ cnt,
                                                        const int* __restrict__ bsum,
                                                        int* __restrict__ row_ptr,
                                                        int* __restrict__ cursor,
                                                        float* __restrict__ dinv) {
  __shared__ int ws[4];
  int tid = threadIdx.x, lane = tid & 63, wid = tid >> 6;
  int v = 0;
  if (tid < SCAN_NB && tid < blockIdx.x) v = bsum[tid];
  v = wave_reduce_sum_i(v);
  if (lane == 0) ws[wid] = v;
  __syncthreads();
  int boff = ws[0] + ws[1] + ws[2] + ws[3];
  int idx = blockIdx.x * SCAN_BS + tid;
  if (idx >= N_NODES) return;
  int val = row_ptr[idx + 1] + boff;
  row_ptr[idx + 1] = val;
  int c = cnt[idx];
  cursor[idx] = val - c;
  dinv[idx] = 1.0f / sqrtf((float)(c + 1));
  if (idx == 0) row_ptr[0] = 0;
}

__global__ void scatter_kernel(const int* __restrict__ src, const int* __restrict__ dst,
                               const float* __restrict__ dinv, int* __restrict__ cursor,
                               int* __restrict__ col, float* __restrict__ ew) {
  int e = blockIdx.x * blockDim.x + threadIdx.x;
  if (e >= N_EDGES) return;
  int s = src[e], d = dst[e];
  int pos = atomicAdd(&cursor[d], 1);
  col[pos] = s;
  ew[pos] = dinv[s] * dinv[d];
}

// ---------------- combined weight convert+transpose (10 matrices, 1 launch) ----

struct WcSeg { const float* W; short* Wt; int K; int Nc; };
struct WcArgs { WcSeg seg[10]; };

__global__ void wconv_all_kernel(WcArgs a) {
  int sidx = blockIdx.y;
  WcSeg s = a.seg[sidx];
  int i = blockIdx.x * blockDim.x + threadIdx.x;
  if (i >= s.K * s.Nc) return;
  int k = i / s.Nc, n = i - k * s.Nc;
  s.Wt[(size_t)n * s.K + k] = f2b(s.W[i]);
}

// ---------------- logmap0 for BOTH branches -> interleaved Ab[node][f:128|s:128] ----

__global__ __launch_bounds__(256) void logmap2_kernel(const float* __restrict__ x,
                                                      const float* __restrict__ x_s,
                                                      short* __restrict__ Ab) {
  int w = blockIdx.x * 4 + (threadIdx.x >> 6);
  int lane = threadIdx.x & 63;
  if (w >= 2 * N_NODES) return;
  int br = (w >= N_NODES) ? 1 : 0;
  int row = br ? (w - N_NODES) : w;
  const float* xr = (br ? x_s : x) + (size_t)row * F_IN;
  float2 v = *(const float2*)(xr + lane * 2);
  float s = wave_reduce_sum(v.x * v.x + v.y * v.y);
  float n = sqrtf(s);
  float nc = fmaxf(n, 1e-15f);
  float f = atanhf(fminf(nc, 0.9999999f)) / nc;
  short2 o; o.x = f2b(v.x * f); o.y = f2b(v.y * f);
  *(short2*)(Ab + (size_t)row * 256 + br * 128 + lane * 2) = o;
}

// ---------------- CSR aggregation, both branches per gather (512B rows) ----------

__global__ __launch_bounds__(256) void agg2_kernel(const short* __restrict__ Xin, int lda,
                                                   const float* __restrict__ dinv,
                                                   const int* __restrict__ row_ptr,
                                                   const int* __restrict__ col,
                                                   const float* __restrict__ ew,
                                                   short* __restrict__ Xa) {
  int node = blockIdx.x * 4 + (threadIdx.x >> 6);
  int lane = threadIdx.x & 63;
  if (node >= N_NODES) return;
  float di = dinv[node];
  float wsf = di * di;
  short4 sv = *(const short4*)(Xin + (size_t)node * lda + lane * 4);
  float a0 = b2f(sv.x) * wsf, a1 = b2f(sv.y) * wsf, a2 = b2f(sv.z) * wsf, a3 = b2f(sv.w) * wsf;
  int s = row_ptr[node], e = row_ptr[node + 1];
  int j = s;
  for (; j + 4 <= e; j += 4) {
    int c0 = col[j], c1 = col[j + 1], c2 = col[j + 2], c3 = col[j + 3];
    float w0 = ew[j], w1 = ew[j + 1], w2 = ew[j + 2], w3 = ew[j + 3];
    short4 v0 = *(const short4*)(Xin + (size_t)c0 * lda + lane * 4);
    short4 v1 = *(const short4*)(Xin + (size_t)c1 * lda + lane * 4);
    short4 v2 = *(const short4*)(Xin + (size_t)c2 * lda + lane * 4);
    short4 v3 = *(const short4*)(Xin + (size_t)c3 * lda + lane * 4);
    a0 += b2f(v0.x) * w0; a1 += b2f(v0.y) * w0; a2 += b2f(v0.z) * w0; a3 += b2f(v0.w) * w0;
    a0 += b2f(v1.x) * w1; a1 += b2f(v1.y) * w1; a2 += b2f(v1.z) * w1; a3 += b2f(v1.w) * w1;
    a0 += b2f(v2.x) * w2; a1 += b2f(v2.y) * w2; a2 += b2f(v2.z) * w2; a3 += b2f(v2.w) * w2;
    a0 += b2f(v3.x) * w3; a1 += b2f(v3.y) * w3; a2 += b2f(v3.z) * w3; a3 += b2f(v3.w) * w3;
  }
  for (; j < e; ++j) {
    float w0 = ew[j];
    short4 v0 = *(const short4*)(Xin + (size_t)col[j] * lda + lane * 4);
    a0 += b2f(v0.x) * w0; a1 += b2f(v0.y) * w0; a2 += b2f(v0.z) * w0; a3 += b2f(v0.w) * w0;
  }
  short4 o; o.x = f2b(a0); o.y = f2b(a1); o.z = f2b(a2); o.w = f2b(a3);
  *(short4*)(Xa + (size_t)node * 256 + lane * 4) = o;
}

// ---------------- bf16 MFMA GEMM, z-batched (2 independent problems) ----------

#define LDK 40  // 32 + 8 pad shorts

struct GemmZArgs {
  const short* A[2];
  const short* Bt[2];
  const float* bias[2];
  short* Cb[2];
  int lda, ldc, M, Nc, K, kexp, do_relu;
};

__global__ __launch_bounds__(256) void mfma_gemmz_kernel(GemmZArgs g) {
  __shared__ __align__(16) short As[128 * LDK];
  __shared__ __align__(16) short Bs[128 * LDK];
  int z = blockIdx.z;
  const short* __restrict__ A = g.A[z];
  const short* __restrict__ Bt = g.Bt[z];
  int tid = threadIdx.x;
  int wave = tid >> 6, lane = tid & 63;
  int wr = (wave >> 1) * 64, wc = (wave & 1) * 64;
  int q = lane >> 4, m = lane & 15;
  int row0 = blockIdx.x * 128, col0 = blockIdx.y * 128;
  f32x4 acc[4][4] = {};
  for (int k0 = 0; k0 < g.K; k0 += 32) {
#pragma unroll
    for (int p = 0; p < 2; ++p) {
      int idx = p * 256 + tid;      // 0..511
      int r = idx >> 2, kc = (idx & 3) * 8;
      int gr = row0 + r;
      int kk = k0 + kc;
      int acol = g.kexp ? (kk + ((kk >> 7) << 7)) : kk;
      float4 v = make_float4(0.f, 0.f, 0.f, 0.f);
      if (gr < g.M) v = *(const float4*)(A + (size_t)gr * g.lda + acol);
      *(float4*)(As + r * LDK + kc) = v;
      float4 w = *(const float4*)(Bt + (size_t)(col0 + r) * g.K + kk);
      *(float4*)(Bs + r * LDK + kc) = w;
    }
    __syncthreads();
    bf16x8 af[4], bfr[4];
#pragma unroll
    for (int i = 0; i < 4; ++i) {
      af[i]  = *(const bf16x8*)(As + (wr + i * 16 + m) * LDK + q * 8);
      bfr[i] = *(const bf16x8*)(Bs + (wc + i * 16 + m) * LDK + q * 8);
    }
#pragma unroll
    for (int i = 0; i < 4; ++i)
#pragma unroll
      for (int j = 0; j < 4; ++j)
        acc[i][j] = __builtin_amdgcn_mfma_f32_16x16x32_bf16(af[i], bfr[j], acc[i][j], 0, 0, 0);
    __syncthreads();
  }
  const float* __restrict__ bias = g.bias[z];
  short* __restrict__ Cb = g.Cb[z];
#pragma unroll
  for (int i = 0; i < 4; ++i) {
#pragma unroll
    for (int r = 0; r < 4; ++r) {
      int rr = row0 + wr + i * 16 + q * 4 + r;
      if (rr >= g.M) continue;
#pragma unroll
      for (int j = 0; j < 4; ++j) {
        int cc = col0 + wc + j * 16 + m;
        float v = acc[i][j][r];
        if (bias) v += bias[cc];
        if (g.do_relu) v = fmaxf(v, 0.0f);
        Cb[(size_t)rr * g.ldc + cc] = f2b(v);
      }
    }
  }
}

// ---------------- fused 2-layer MLP head + expmap0/proj epilogue ----------------
// out = expproj( relu(A @ B1^T) @ B2^T ), per block: 128 rows x full 384x384.
// 512 thr, 8 waves; wave = 64 rows (rg=wave&1, 2x32-row frags) x 96 cols
// (cq=wave>>1, 3x32-col frags), 32x32x16 MFMA, acc f32x16[2][3].
// Operands STAGED IN LDS (round-8's direct-global B reads were scatter-class:
// 32 lanes x 768B stride = 32 lines/instr -> VMEM-bound, 7% MfmaUtil).
// 5 ds_read_b128 feed 6 MFMAs per k16 -> LDS BW ~= MFMA demand (balanced).
// Hidden H (bf16 128x392) in LDS between stages. 32x32x16 layouts verified in
// round 8 (passed): A row=lane&31, k=(lane>>5)*8+e; C/D col=lane&31,
// row=(reg&3)+8*(reg>>2)+4*(lane>>5).
// Extra blocks (x >= gx_h, z==0) run the g-head problem p[2].

#define HLD 392  // 384 + 8 pad shorts

struct MlpProb {
  const short* A;
  const short* B1;     // [384][K1]
  const short* B2;     // [384][384]
  float* Cf;
  float* Cf2;
  int lda, M, K1, kexp, split;
};
struct Mlp2Args { MlpProb p[3]; int gx_h; };

__global__ __launch_bounds__(512) void mlp2_kernel(Mlp2Args g) {
  __shared__ __align__(16) short As[128 * LDK];
  __shared__ __align__(16) short Bs[384 * LDK];
  __shared__ __align__(16) short H[128 * HLD];
  __shared__ float nsum[128][4];
  int z = blockIdx.z;
  int bx = blockIdx.x;
  MlpProb p;
  int row0;
  if (bx < g.gx_h) { p = g.p[z]; row0 = bx * 128; }
  else { if (z) return; p = g.p[2]; row0 = (bx - g.gx_h) * 128; }

  int tid = threadIdx.x;
  int wave = tid >> 6, lane = tid & 63;
  int l31 = lane & 31, lh = lane >> 5;
  int rg = wave & 1;   // row group: rows rg*64..+63
  int cq = wave >> 1;  // col quarter: cols cq*96..+95

  f32x16 acc[2][3] = {};
  // ---- stage 1: hidden = relu(A @ B1^T), K = K1, LDS-staged K-tiles of 32 ----
  for (int k0 = 0; k0 < p.K1; k0 += 32) {
    {
      int r = tid >> 2, kc = (tid & 3) * 8;   // As: 128 rows x 32 k
      int gr = row0 + r;
      int kk = k0 + kc;
      int acol = p.kexp ? (kk + ((kk >> 7) << 7)) : kk;
      float4 v = make_float4(0.f, 0.f, 0.f, 0.f);
      if (gr < p.M) v = *(const float4*)(p.A + (size_t)gr * p.lda + acol);
      *(float4*)(As + r * LDK + kc) = v;
    }
#pragma unroll
    for (int q = 0; q < 3; ++q) {            // Bs: 384 rows x 32 k
      int idx = q * 512 + tid;
      int r = idx >> 2, kc = (idx & 3) * 8;
      float4 w0 = *(const float4*)(p.B1 + (size_t)r * p.K1 + k0 + kc);
      *(float4*)(Bs + r * LDK + kc) = w0;
    }
    __syncthreads();
#pragma unroll
    for (int ks = 0; ks < 32; ks += 16) {
      int kloc = ks + lh * 8;
      bf16x8 a0 = *(const bf16x8*)(As + (rg * 64 + l31) * LDK + kloc);
      bf16x8 a1 = *(const bf16x8*)(As + (rg * 64 + 32 + l31) * LDK + kloc);
      bf16x8 b0 = *(const bf16x8*)(Bs + (cq * 96 + l31) * LDK + kloc);
      bf16x8 b1 = *(const bf16x8*)(Bs + (cq * 96 + 32 + l31) * LDK + kloc);
      bf16x8 b2 = *(const bf16x8*)(Bs + (cq * 96 + 64 + l31) * LDK + kloc);
      acc[0][0] = __builtin_amdgcn_mfma_f32_32x32x16_bf16(a0, b0, acc[0][0], 0, 0, 0);
      acc[1][0] = __builtin_amdgcn_mfma_f32_32x32x16_bf16(a1, b0, acc[1][0], 0, 0, 0);
      acc[0][1] = __builtin_amdgcn_mfma_f32_32x32x16_bf16(a0, b1, acc[0][1], 0, 0, 0);
      acc[1][1] = __builtin_amdgcn_mfma_f32_32x32x16_bf16(a1, b1, acc[1][1], 0, 0, 0);
      acc[0][2] = __builtin_amdgcn_mfma_f32_32x32x16_bf16(a0, b2, acc[0][2], 0, 0, 0);
      acc[1][2] = __builtin_amdgcn_mfma_f32_32x32x16_bf16(a1, b2, acc[1][2], 0, 0, 0);
    }
    __syncthreads();
  }
  // ---- relu + bf16 hidden -> LDS H ----
#pragma unroll
  for (int rf = 0; rf < 2; ++rf)
#pragma unroll
    for (int f = 0; f < 3; ++f)
#pragma unroll
      for (int reg = 0; reg < 16; ++reg) {
        int rl = rg * 64 + rf * 32 + (reg & 3) + 8 * (reg >> 2) + 4 * lh;
        H[rl * HLD + cq * 96 + f * 32 + l31] = f2b(fmaxf(acc[rf][f][reg], 0.0f));
      }
#pragma unroll
  for (int rf = 0; rf < 2; ++rf)
#pragma unroll
    for (int f = 0; f < 3; ++f) acc[rf][f] = (f32x16){};
  __syncthreads();
  // ---- stage 2: out = H @ B2^T, K = 384; A from H, B staged in LDS ----
  for (int k0 = 0; k0 < 384; k0 += 32) {
#pragma unroll
    for (int q = 0; q < 3; ++q) {
      int idx = q * 512 + tid;
      int r = idx >> 2, kc = (idx & 3) * 8;
      float4 w0 = *(const float4*)(p.B2 + (size_t)r * 384 + k0 + kc);
      *(float4*)(Bs + r * LDK + kc) = w0;
    }
    __syncthreads();
#pragma unroll
    for (int ks = 0; ks < 32; ks += 16) {
      int kloc = ks + lh * 8;
      bf16x8 a0 = *(const bf16x8*)(H + (rg * 64 + l31) * HLD + k0 + kloc);
      bf16x8 a1 = *(const bf16x8*)(H + (rg * 64 + 32 + l31) * HLD + k0 + kloc);
      bf16x8 b0 = *(const bf16x8*)(Bs + (cq * 96 + l31) * LDK + kloc);
      bf16x8 b1 = *(const bf16x8*)(Bs + (cq * 96 + 32 + l31) * LDK + kloc);
      bf16x8 b2 = *(const bf16x8*)(Bs + (cq * 96 + 64 + l31) * LDK + kloc);
      acc[0][0] = __builtin_amdgcn_mfma_f32_32x32x16_bf16(a0, b0, acc[0][0], 0, 0, 0);
      acc[1][0] = __builtin_amdgcn_mfma_f32_32x32x16_bf16(a1, b0, acc[1][0], 0, 0, 0);
      acc[0][1] = __builtin_amdgcn_mfma_f32_32x32x16_bf16(a0, b1, acc[0][1], 0, 0, 0);
      acc[1][1] = __builtin_amdgcn_mfma_f32_32x32x16_bf16(a1, b1, acc[1][1], 0, 0, 0);
      acc[0][2] = __builtin_amdgcn_mfma_f32_32x32x16_bf16(a0, b2, acc[0][2], 0, 0, 0);
      acc[1][2] = __builtin_amdgcn_mfma_f32_32x32x16_bf16(a1, b2, acc[1][2], 0, 0, 0);
    }
    __syncthreads();
  }
  // ---- per-row norm partials (this wave's 96-col quarter) ----
#pragma unroll
  for (int rf = 0; rf < 2; ++rf)
#pragma unroll
    for (int reg = 0; reg < 16; ++reg) {
      float s = acc[rf][0][reg] * acc[rf][0][reg] + acc[rf][1][reg] * acc[rf][1][reg] +
                acc[rf][2][reg] * acc[rf][2][reg];
      s += __shfl_xor(s, 1, 64);
      s += __shfl_xor(s, 2, 64);
      s += __shfl_xor(s, 4, 64);
      s += __shfl_xor(s, 8, 64);
      s += __shfl_xor(s, 16, 64);
      if (l31 == 0)
        nsum[rg * 64 + rf * 32 + (reg & 3) + 8 * (reg >> 2) + 4 * lh][cq] = s;
    }
  __syncthreads();
  // ---- expmap0 + proj + store ----
  const float maxn = 1.0f - 4e-3f;
#pragma unroll
  for (int rf = 0; rf < 2; ++rf)
#pragma unroll
    for (int reg = 0; reg < 16; ++reg) {
      int rl = rg * 64 + rf * 32 + (reg & 3) + 8 * (reg >> 2) + 4 * lh;
      int rr = row0 + rl;
      if (rr >= p.M) continue;
      float s = nsum[rl][0] + nsum[rl][1] + nsum[rl][2] + nsum[rl][3];
      float n = fmaxf(sqrtf(s), 1e-15f);
      float th = tanhf(n);
      float fct = th / n;
      float n2 = fmaxf(th, 1e-15f);
      if (n2 > maxn) fct *= maxn / n2;
      float* base = (rr < p.split) ? (p.Cf + (size_t)rr * 384)
                                   : (p.Cf2 + (size_t)(rr - p.split) * 384);
#pragma unroll
      for (int f = 0; f < 3; ++f)
        base[cq * 96 + f * 32 + l31] = acc[rf][f][reg] * fct;
    }
}

// ---------------- global_add_pool over sorted batch, interleaved layout ----------

__global__ __launch_bounds__(768) void pool2_kernel(const short* __restrict__ NB,
                                                    const int* __restrict__ gptr,
                                                    short* __restrict__ GCb,
                                                    short* __restrict__ nbappend) {
  int g = blockIdx.x, t = threadIdx.x;  // t in [0,768)
  int s = gptr[g], e = gptr[g + 1];
  float acc = 0.0f;
  for (int i = s; i < e; ++i) acc += b2f(NB[(size_t)i * 768 + t]);
  short bv = f2b(acc);
  int l = t >> 8, rem = t & 255, b = rem >> 7, c = rem & 127;
  GCb[(size_t)g * 768 + b * 384 + l * 128 + c] = bv;
  nbappend[(size_t)g * 768 + t] = bv;
}

// ---------------- driver ----------------

extern "C" void kernel_launch(void* const* d_in, const int* in_sizes, int n_in,
                              void* d_out, int out_size, void* d_ws, size_t ws_size,
                              hipStream_t stream) {
  (void)in_sizes; (void)n_in; (void)out_size; (void)ws_size;
  const float* x   = (const float*)d_in[0];
  const float* x_s = (const float*)d_in[1];
  const int* src   = (const int*)d_in[2];
  const int* dst   = (const int*)d_in[3];
  const int* batch = (const int*)d_in[4];
  const float* Wf[3] = {(const float*)d_in[5], (const float*)d_in[6], (const float*)d_in[7]};
  const float* bf[3] = {(const float*)d_in[8], (const float*)d_in[9], (const float*)d_in[10]};
  const float* Wsb[3] = {(const float*)d_in[11], (const float*)d_in[12], (const float*)d_in[13]};
  const float* bs[3] = {(const float*)d_in[14], (const float*)d_in[15], (const float*)d_in[16]};
  const float* P1 = (const float*)d_in[17];
  const float* P2 = (const float*)d_in[18];
  const float* G1 = (const float*)d_in[19];
  const float* G2 = (const float*)d_in[20];
  float* out = (float*)d_out;

  char* w = (char*)d_ws;
  auto alloc = [&](size_t bytes) {
    char* p = w;
    w += (bytes + 255) & ~(size_t)255;
    return p;
  };
  short* Ab    = (short*)alloc((size_t)N_NODES * 256 * 2);   // logmap out, interleaved
  short* Xa    = (short*)alloc((size_t)N_NODES * 256 * 2);   // aggregated, interleaved
  short* NB    = (short*)alloc((size_t)M_ALL * 768 * 2);     // [row][l][branch][128]
  int* cnt     = (int*)alloc((size_t)N_NODES * 4);
  int* row_ptr = (int*)alloc((size_t)(N_NODES + 1) * 4);
  int* cursor  = (int*)alloc((size_t)N_NODES * 4);
  float* dinv  = (float*)alloc((size_t)N_NODES * 4);
  int* col     = (int*)alloc((size_t)N_EDGES * 4);
  float* ew    = (float*)alloc((size_t)N_EDGES * 4);
  int* gptr    = (int*)alloc((size_t)(N_GRAPHS + 1) * 4);
  int* bsum    = (int*)alloc(256 * 4);
  short* GCb   = (short*)alloc((size_t)N_GRAPHS * 768 * 2);
  short* P1t   = (short*)alloc((size_t)EDIM * EDIM * 2);
  short* P2t   = (short*)alloc((size_t)EDIM * EDIM * 2);
  short* G1t   = (short*)alloc((size_t)768 * EDIM * 2);
  short* G2t   = (short*)alloc((size_t)EDIM * EDIM * 2);
  short* Wft[3], *Wst[3];
  for (int l = 0; l < 3; ++l) {
    Wft[l] = (short*)alloc((size_t)128 * 128 * 2);
    Wst[l] = (short*)alloc((size_t)128 * 128 * 2);
  }

  // ---- weight convert (independent of graph) ----
  {
    WcArgs wa;
    wa.seg[0] = {P1, P1t, EDIM, EDIM};
    wa.seg[1] = {P2, P2t, EDIM, EDIM};
    wa.seg[2] = {G1, G1t, 768, EDIM};
    wa.seg[3] = {G2, G2t, EDIM, EDIM};
    for (int l = 0; l < 3; ++l) {
      wa.seg[4 + l] = {Wf[l], Wft[l], 128, 128};
      wa.seg[7 + l] = {Wsb[l], Wst[l], 128, 128};
    }
    wconv_all_kernel<<<dim3((768 * EDIM + 255) / 256, 10), 256, 0, stream>>>(wa);
  }

  // ---- graph structure: 5 launches ----
  init_kernel<<<SCAN_NB, SCAN_BS, 0, stream>>>(batch, cnt, gptr);
  hist_kernel<<<(N_EDGES + 255) / 256, 256, 0, stream>>>(dst, cnt);
  scan1_kernel<<<SCAN_NB, SCAN_BS, 0, stream>>>(cnt, row_ptr, bsum);
  scan3_kernel<<<SCAN_NB, SCAN_BS, 0, stream>>>(cnt, bsum, row_ptr, cursor, dinv);
  scatter_kernel<<<(N_EDGES + 255) / 256, 256, 0, stream>>>(src, dst, dinv, cursor, col, ew);

  const size_t OUT0 = 0;
  const size_t OUT1 = (size_t)N_GRAPHS * EDIM;
  const size_t OUT2 = OUT1 + (size_t)N_GRAPHS * EDIM;
  const size_t OUT3 = OUT2 + (size_t)N_NODES * EDIM;

  const int gx_layer = (N_NODES + 127) / 128;   // 391
  const int gx_mfma  = (M_ALL + 127) / 128;     // 395
  const int gx_agg   = (N_NODES + 3) / 4;       // 12500

  // ---- logmap both branches -> interleaved Ab ----
  logmap2_kernel<<<(2 * N_NODES + 3) / 4, 256, 0, stream>>>(x, x_s, Ab);

  // ---- 3 GCN layers, both branches per launch ----
  const short* cur = Ab;
  int clda = 256;
  for (int l = 0; l < 3; ++l) {
    agg2_kernel<<<gx_agg, 256, 0, stream>>>(cur, clda, dinv, row_ptr, col, ew, Xa);
    GemmZArgs ga = {};
    ga.A[0] = Xa;        ga.A[1] = Xa + 128;
    ga.Bt[0] = Wft[l];   ga.Bt[1] = Wst[l];
    ga.bias[0] = bf[l];  ga.bias[1] = bs[l];
    ga.Cb[0] = NB + l * 256;        ga.Cb[1] = NB + l * 256 + 128;
    ga.lda = 256; ga.ldc = 768; ga.M = N_NODES; ga.Nc = 128; ga.K = 128;
    ga.kexp = 0; ga.do_relu = 1;
    mfma_gemmz_kernel<<<dim3(gx_layer, 1, 2), 256, 0, stream>>>(ga);
    cur = NB + l * 256;
    clda = 768;
  }

  // ---- pool (both branches) + append pooled rows to NB ----
  pool2_kernel<<<N_GRAPHS, 768, 0, stream>>>(NB, gptr, GCb, NB + (size_t)N_NODES * 768);

  // ---- all MLP heads in ONE dispatch: z=0/1 node+graph heads, tail-x = g head ----
  {
    const int gx_g = (N_GRAPHS + 127) / 128;  // 4
    Mlp2Args h = {};
    h.p[0] = {NB,       P1t, P2t, out + OUT2,
              out + OUT1, 768, M_ALL, EDIM, 1, N_NODES};
    h.p[1] = {NB + 128, P1t, P2t, out + OUT3 + (size_t)N_GRAPHS * EDIM,
              out + OUT3, 768, M_ALL, EDIM, 1, N_NODES};
    h.p[2] = {GCb, G1t, G2t, out + OUT0, out + OUT0, 768, N_GRAPHS, 768, 0, 1 << 30};
    h.gx_h = gx_mfma;
    mlp2_kernel<<<dim3(gx_mfma + gx_g, 1, 2), 512, 0, stream>>>(h);
  }
}

// Round 10
// 718.238 us; speedup vs baseline: 1.1634x; 1.0424x over previous
//
#include <hip/hip_runtime.h>
#include <math.h>

#define N_NODES 50000
#define N_EDGES 600000
#define N_GRAPHS 512
#define F_IN 128
#define D_HID 128
#define EDIM 384
#define M_ALL (N_NODES + N_GRAPHS)  // node rows + appended pooled graph rows

typedef __attribute__((ext_vector_type(8))) short bf16x8;
typedef __attribute__((ext_vector_type(4))) float f32x4;
typedef __attribute__((ext_vector_type(16))) float f32x16;

static __device__ __forceinline__ float wave_reduce_sum(float s) {
#pragma unroll
  for (int off = 32; off > 0; off >>= 1) s += __shfl_xor(s, off, 64);
  return s;
}

static __device__ __forceinline__ int wave_reduce_sum_i(int s) {
#pragma unroll
  for (int off = 32; off > 0; off >>= 1) s += __shfl_xor(s, off, 64);
  return s;
}

static __device__ __forceinline__ short f2b(float f) {
  unsigned u = __float_as_uint(f);
  unsigned r = (u + 0x7FFFu + ((u >> 16) & 1u)) >> 16;
  return (short)r;
}

static __device__ __forceinline__ float b2f(short s) {
  return __uint_as_float(((unsigned)(unsigned short)s) << 16);
}

// ---------------- graph preprocessing ----------------

#define SCAN_BS 256
#define SCAN_NB ((N_NODES + SCAN_BS - 1) / SCAN_BS)  // 196

// zero cnt + compute gptr (binary search over sorted batch), one launch
__global__ __launch_bounds__(SCAN_BS) void init_kernel(const int* __restrict__ batch,
                                                       int* __restrict__ cnt,
                                                       int* __restrict__ gptr) {
  int i = blockIdx.x * SCAN_BS + threadIdx.x;
  if (i < N_NODES) cnt[i] = 0;
  if (i <= N_GRAPHS) {
    int lo = 0, hi = N_NODES;
    while (lo < hi) { int mid = (lo + hi) >> 1; if (batch[mid] < i) lo = mid + 1; else hi = mid; }
    gptr[i] = lo;
  }
}

__global__ void hist_kernel(const int* __restrict__ dst, int* __restrict__ cnt) {
  int i = blockIdx.x * blockDim.x + threadIdx.x;
  if (i < N_EDGES) atomicAdd(&cnt[dst[i]], 1);
}

__global__ __launch_bounds__(SCAN_BS) void scan1_kernel(const int* __restrict__ cnt,
                                                        int* __restrict__ row_ptr,
                                                        int* __restrict__ bsum) {
  __shared__ int wsum[4];
  int tid = threadIdx.x, lane = tid & 63, wid = tid >> 6;
  int idx = blockIdx.x * SCAN_BS + tid;
  int v = (idx < N_NODES) ? cnt[idx] : 0;
  int x = v;
#pragma unroll
  for (int off = 1; off < 64; off <<= 1) {
    int t = __shfl_up(x, off, 64);
    if (lane >= off) x += t;
  }
  if (lane == 63) wsum[wid] = x;
  __syncthreads();
  int pre = 0, tot = 0;
#pragma unroll
  for (int w = 0; w < 4; ++w) { int s = wsum[w]; tot += s; if (w < wid) pre += s; }
  if (idx < N_NODES) row_ptr[idx + 1] = x + pre;  // block-local inclusive
  if (tid == 0) bsum[blockIdx.x] = tot;
}

// scan3 with fused scan2 (local re-reduction of bsum prefix) + fused dinv
__global__ __launch_bounds__(SCAN_BS) void scan3_kernel(const int* __restrict__ cnt,
                                                        const int* __restrict__ bsum,
                                                        int* __restrict__ row_ptr,
                                                        int* __restrict__ cursor,
                                                        float* __restrict__ dinv) {
  __shared__ int ws[4];
  int tid = threadIdx.x, lane = tid & 63, wid = tid >> 6;
  int v = 0;
  if (tid < SCAN_NB && tid < blockIdx.x) v = bsum[tid];
  v = wave_reduce_sum_i(v);
  if (lane == 0) ws[wid] = v;
  __syncthreads();
  int boff = ws[0] + ws[1] + ws[2] + ws[3];
  int idx = blockIdx.x * SCAN_BS + tid;
  if (idx >= N_NODES) return;
  int val = row_ptr[idx + 1] + boff;
  row_ptr[idx + 1] = val;
  int c = cnt[idx];
  cursor[idx] = val - c;
  dinv[idx] = 1.0f / sqrtf((float)(c + 1));
  if (idx == 0) row_ptr[0] = 0;
}

__global__ void scatter_kernel(const int* __restrict__ src, const int* __restrict__ dst,
                               const float* __restrict__ dinv, int* __restrict__ cursor,
                               int* __restrict__ col, float* __restrict__ ew) {
  int e = blockIdx.x * blockDim.x + threadIdx.x;
  if (e >= N_EDGES) return;
  int s = src[e], d = dst[e];
  int pos = atomicAdd(&cursor[d], 1);
  col[pos] = s;
  ew[pos] = dinv[s] * dinv[d];
}

// ---------------- combined weight convert+transpose (10 matrices, 1 launch) ----

struct WcSeg { const float* W; short* Wt; int K; int Nc; };
struct WcArgs { WcSeg seg[10]; };

__global__ void wconv_all_kernel(WcArgs a) {
  int sidx = blockIdx.y;
  WcSeg s = a.seg[sidx];
  int i = blockIdx.x * blockDim.x + threadIdx.x;
  if (i >= s.K * s.Nc) return;
  int k = i / s.Nc, n = i - k * s.Nc;
  s.Wt[(size_t)n * s.K + k] = f2b(s.W[i]);
}

// ---------------- logmap0 for BOTH branches -> interleaved Ab[node][f:128|s:128] ----

__global__ __launch_bounds__(256) void logmap2_kernel(const float* __restrict__ x,
                                                      const float* __restrict__ x_s,
                                                      short* __restrict__ Ab) {
  int w = blockIdx.x * 4 + (threadIdx.x >> 6);
  int lane = threadIdx.x & 63;
  if (w >= 2 * N_NODES) return;
  int br = (w >= N_NODES) ? 1 : 0;
  int row = br ? (w - N_NODES) : w;
  const float* xr = (br ? x_s : x) + (size_t)row * F_IN;
  float2 v = *(const float2*)(xr + lane * 2);
  float s = wave_reduce_sum(v.x * v.x + v.y * v.y);
  float n = sqrtf(s);
  float nc = fmaxf(n, 1e-15f);
  float f = atanhf(fminf(nc, 0.9999999f)) / nc;
  short2 o; o.x = f2b(v.x * f); o.y = f2b(v.y * f);
  *(short2*)(Ab + (size_t)row * 256 + br * 128 + lane * 2) = o;
}

// ---------------- CSR aggregation, both branches per gather (512B rows) ----------

__global__ __launch_bounds__(256) void agg2_kernel(const short* __restrict__ Xin, int lda,
                                                   const float* __restrict__ dinv,
                                                   const int* __restrict__ row_ptr,
                                                   const int* __restrict__ col,
                                                   const float* __restrict__ ew,
                                                   short* __restrict__ Xa) {
  int node = blockIdx.x * 4 + (threadIdx.x >> 6);
  int lane = threadIdx.x & 63;
  if (node >= N_NODES) return;
  float di = dinv[node];
  float wsf = di * di;
  short4 sv = *(const short4*)(Xin + (size_t)node * lda + lane * 4);
  float a0 = b2f(sv.x) * wsf, a1 = b2f(sv.y) * wsf, a2 = b2f(sv.z) * wsf, a3 = b2f(sv.w) * wsf;
  int s = row_ptr[node], e = row_ptr[node + 1];
  int j = s;
  for (; j + 4 <= e; j += 4) {
    int c0 = col[j], c1 = col[j + 1], c2 = col[j + 2], c3 = col[j + 3];
    float w0 = ew[j], w1 = ew[j + 1], w2 = ew[j + 2], w3 = ew[j + 3];
    short4 v0 = *(const short4*)(Xin + (size_t)c0 * lda + lane * 4);
    short4 v1 = *(const short4*)(Xin + (size_t)c1 * lda + lane * 4);
    short4 v2 = *(const short4*)(Xin + (size_t)c2 * lda + lane * 4);
    short4 v3 = *(const short4*)(Xin + (size_t)c3 * lda + lane * 4);
    a0 += b2f(v0.x) * w0; a1 += b2f(v0.y) * w0; a2 += b2f(v0.z) * w0; a3 += b2f(v0.w) * w0;
    a0 += b2f(v1.x) * w1; a1 += b2f(v1.y) * w1; a2 += b2f(v1.z) * w1; a3 += b2f(v1.w) * w1;
    a0 += b2f(v2.x) * w2; a1 += b2f(v2.y) * w2; a2 += b2f(v2.z) * w2; a3 += b2f(v2.w) * w2;
    a0 += b2f(v3.x) * w3; a1 += b2f(v3.y) * w3; a2 += b2f(v3.z) * w3; a3 += b2f(v3.w) * w3;
  }
  for (; j < e; ++j) {
    float w0 = ew[j];
    short4 v0 = *(const short4*)(Xin + (size_t)col[j] * lda + lane * 4);
    a0 += b2f(v0.x) * w0; a1 += b2f(v0.y) * w0; a2 += b2f(v0.z) * w0; a3 += b2f(v0.w) * w0;
  }
  short4 o; o.x = f2b(a0); o.y = f2b(a1); o.z = f2b(a2); o.w = f2b(a3);
  *(short4*)(Xa + (size_t)node * 256 + lane * 4) = o;
}

// ---------------- bf16 MFMA GEMM, z-batched (2 independent problems) ----------

#define LDK 40  // 32 + 8 pad shorts

struct GemmZArgs {
  const short* A[2];
  const short* Bt[2];
  const float* bias[2];
  short* Cb[2];
  int lda, ldc, M, Nc, K, kexp, do_relu;
};

__global__ __launch_bounds__(256) void mfma_gemmz_kernel(GemmZArgs g) {
  __shared__ __align__(16) short As[128 * LDK];
  __shared__ __align__(16) short Bs[128 * LDK];
  int z = blockIdx.z;
  const short* __restrict__ A = g.A[z];
  const short* __restrict__ Bt = g.Bt[z];
  int tid = threadIdx.x;
  int wave = tid >> 6, lane = tid & 63;
  int wr = (wave >> 1) * 64, wc = (wave & 1) * 64;
  int q = lane >> 4, m = lane & 15;
  int row0 = blockIdx.x * 128, col0 = blockIdx.y * 128;
  f32x4 acc[4][4] = {};
  for (int k0 = 0; k0 < g.K; k0 += 32) {
#pragma unroll
    for (int p = 0; p < 2; ++p) {
      int idx = p * 256 + tid;      // 0..511
      int r = idx >> 2, kc = (idx & 3) * 8;
      int gr = row0 + r;
      int kk = k0 + kc;
      int acol = g.kexp ? (kk + ((kk >> 7) << 7)) : kk;
      float4 v = make_float4(0.f, 0.f, 0.f, 0.f);
      if (gr < g.M) v = *(const float4*)(A + (size_t)gr * g.lda + acol);
      *(float4*)(As + r * LDK + kc) = v;
      float4 w = *(const float4*)(Bt + (size_t)(col0 + r) * g.K + kk);
      *(float4*)(Bs + r * LDK + kc) = w;
    }
    __syncthreads();
    bf16x8 af[4], bfr[4];
#pragma unroll
    for (int i = 0; i < 4; ++i) {
      af[i]  = *(const bf16x8*)(As + (wr + i * 16 + m) * LDK + q * 8);
      bfr[i] = *(const bf16x8*)(Bs + (wc + i * 16 + m) * LDK + q * 8);
    }
#pragma unroll
    for (int i = 0; i < 4; ++i)
#pragma unroll
      for (int j = 0; j < 4; ++j)
        acc[i][j] = __builtin_amdgcn_mfma_f32_16x16x32_bf16(af[i], bfr[j], acc[i][j], 0, 0, 0);
    __syncthreads();
  }
  const float* __restrict__ bias = g.bias[z];
  short* __restrict__ Cb = g.Cb[z];
#pragma unroll
  for (int i = 0; i < 4; ++i) {
#pragma unroll
    for (int r = 0; r < 4; ++r) {
      int rr = row0 + wr + i * 16 + q * 4 + r;
      if (rr >= g.M) continue;
#pragma unroll
      for (int j = 0; j < 4; ++j) {
        int cc = col0 + wc + j * 16 + m;
        float v = acc[i][j][r];
        if (bias) v += bias[cc];
        if (g.do_relu) v = fmaxf(v, 0.0f);
        Cb[(size_t)rr * g.ldc + cc] = f2b(v);
      }
    }
  }
}

// ---------------- fused 2-layer MLP head + expmap0/proj epilogue ----------------
// out = expproj( relu(A @ B1^T) @ B2^T ), per block: 128 rows x full 384x384.
// 512 thr, 8 waves; wave = 64 rows (rg=wave&1) x 96 cols (cq=wave>>1),
// 32x32x16 MFMA, acc f32x16[2][3]. Operands staged in LDS (round-9 verified).
// NEW (T14): per K-tile, staging = {ds_write regs -> issue NEXT tile's global
// loads -> lgkmcnt(0) + sched_barrier + RAW s_barrier}. Raw barrier does NOT
// drain vmcnt, so prefetch loads fly over compute (at 1 block/CU there is no
// other block to hide latency -- round-9's 61us/block vs 10us modeled work
// was exposed global latency at the __syncthreads vmcnt(0) drain).
// Correctness: lgkmcnt(0) orders LDS writes before barrier; ds_reads complete
// before their consuming MFMAs (compiler waitcnt) hence before the trailing
// barrier; prefetch targets registers only (per-thread dependence).
// Extra blocks (x >= gx_h, z==0) run the g-head problem p[2].

#define HLD 392  // 384 + 8 pad shorts

struct MlpProb {
  const short* A;
  const short* B1;     // [384][K1]
  const short* B2;     // [384][384]
  float* Cf;
  float* Cf2;
  int lda, M, K1, kexp, split;
};
struct Mlp2Args { MlpProb p[3]; int gx_h; };

__global__ __launch_bounds__(512) void mlp2_kernel(Mlp2Args g) {
  __shared__ __align__(16) short As[128 * LDK];
  __shared__ __align__(16) short Bs[384 * LDK];
  __shared__ __align__(16) short H[128 * HLD];
  __shared__ float nsum[128][4];
  int z = blockIdx.z;
  int bx = blockIdx.x;
  MlpProb p;
  int row0;
  if (bx < g.gx_h) { p = g.p[z]; row0 = bx * 128; }
  else { if (z) return; p = g.p[2]; row0 = (bx - g.gx_h) * 128; }

  int tid = threadIdx.x;
  int wave = tid >> 6, lane = tid & 63;
  int l31 = lane & 31, lh = lane >> 5;
  int rg = wave & 1;   // row group: rows rg*64..+63
  int cq = wave >> 1;  // col quarter: cols cq*96..+95

  int r_a = tid >> 2, kc_a = (tid & 3) * 8;  // staging slot (per thread)

  auto loadA1 = [&](int k0) {
    int gr = row0 + r_a;
    int kk = k0 + kc_a;
    int acol = p.kexp ? (kk + ((kk >> 7) << 7)) : kk;
    float4 v = make_float4(0.f, 0.f, 0.f, 0.f);
    if (gr < p.M) v = *(const float4*)(p.A + (size_t)gr * p.lda + acol);
    return v;
  };

  f32x16 acc[2][3] = {};
  float4 pa, pb0, pb1, pb2;
  // ---- prologue: prefetch tile 0 ----
  pa = loadA1(0);
  pb0 = *(const float4*)(p.B1 + (size_t)(0 * 128 + r_a) * p.K1 + kc_a);
  pb1 = *(const float4*)(p.B1 + (size_t)(1 * 128 + r_a) * p.K1 + kc_a);
  pb2 = *(const float4*)(p.B1 + (size_t)(2 * 128 + r_a) * p.K1 + kc_a);

  // ---- stage 1: hidden = relu(A @ B1^T), K = K1, K-tiles of 32, prefetched ----
  for (int k0 = 0; k0 < p.K1; k0 += 32) {
    *(float4*)(As + r_a * LDK + kc_a) = pa;
    *(float4*)(Bs + (0 * 128 + r_a) * LDK + kc_a) = pb0;
    *(float4*)(Bs + (1 * 128 + r_a) * LDK + kc_a) = pb1;
    *(float4*)(Bs + (2 * 128 + r_a) * LDK + kc_a) = pb2;
    int kn = k0 + 32;
    if (kn < p.K1) {               // prefetch next B1/A tile
      pa = loadA1(kn);
      pb0 = *(const float4*)(p.B1 + (size_t)(0 * 128 + r_a) * p.K1 + kn + kc_a);
      pb1 = *(const float4*)(p.B1 + (size_t)(1 * 128 + r_a) * p.K1 + kn + kc_a);
      pb2 = *(const float4*)(p.B1 + (size_t)(2 * 128 + r_a) * p.K1 + kn + kc_a);
    } else {                       // prefetch stage-2 tile 0 (B2)
      pb0 = *(const float4*)(p.B2 + (size_t)(0 * 128 + r_a) * 384 + kc_a);
      pb1 = *(const float4*)(p.B2 + (size_t)(1 * 128 + r_a) * 384 + kc_a);
      pb2 = *(const float4*)(p.B2 + (size_t)(2 * 128 + r_a) * 384 + kc_a);
    }
    asm volatile("s_waitcnt lgkmcnt(0)" ::: "memory");
    __builtin_amdgcn_sched_barrier(0);
    __builtin_amdgcn_s_barrier();
#pragma unroll
    for (int ks = 0; ks < 32; ks += 16) {
      int kloc = ks + lh * 8;
      bf16x8 a0 = *(const bf16x8*)(As + (rg * 64 + l31) * LDK + kloc);
      bf16x8 a1 = *(const bf16x8*)(As + (rg * 64 + 32 + l31) * LDK + kloc);
      bf16x8 b0 = *(const bf16x8*)(Bs + (cq * 96 + l31) * LDK + kloc);
      bf16x8 b1 = *(const bf16x8*)(Bs + (cq * 96 + 32 + l31) * LDK + kloc);
      bf16x8 b2 = *(const bf16x8*)(Bs + (cq * 96 + 64 + l31) * LDK + kloc);
      acc[0][0] = __builtin_amdgcn_mfma_f32_32x32x16_bf16(a0, b0, acc[0][0], 0, 0, 0);
      acc[1][0] = __builtin_amdgcn_mfma_f32_32x32x16_bf16(a1, b0, acc[1][0], 0, 0, 0);
      acc[0][1] = __builtin_amdgcn_mfma_f32_32x32x16_bf16(a0, b1, acc[0][1], 0, 0, 0);
      acc[1][1] = __builtin_amdgcn_mfma_f32_32x32x16_bf16(a1, b1, acc[1][1], 0, 0, 0);
      acc[0][2] = __builtin_amdgcn_mfma_f32_32x32x16_bf16(a0, b2, acc[0][2], 0, 0, 0);
      acc[1][2] = __builtin_amdgcn_mfma_f32_32x32x16_bf16(a1, b2, acc[1][2], 0, 0, 0);
    }
    __builtin_amdgcn_s_barrier();
  }
  // ---- relu + bf16 hidden -> LDS H (B2 tile-0 prefetch already in flight) ----
#pragma unroll
  for (int rf = 0; rf < 2; ++rf)
#pragma unroll
    for (int f = 0; f < 3; ++f)
#pragma unroll
      for (int reg = 0; reg < 16; ++reg) {
        int rl = rg * 64 + rf * 32 + (reg & 3) + 8 * (reg >> 2) + 4 * lh;
        H[rl * HLD + cq * 96 + f * 32 + l31] = f2b(fmaxf(acc[rf][f][reg], 0.0f));
      }
#pragma unroll
  for (int rf = 0; rf < 2; ++rf)
#pragma unroll
    for (int f = 0; f < 3; ++f) acc[rf][f] = (f32x16){};
  asm volatile("s_waitcnt lgkmcnt(0)" ::: "memory");
  __builtin_amdgcn_sched_barrier(0);
  __builtin_amdgcn_s_barrier();
  // ---- stage 2: out = H @ B2^T, K = 384; B2 tiles prefetched ----
  for (int k0 = 0; k0 < 384; k0 += 32) {
    *(float4*)(Bs + (0 * 128 + r_a) * LDK + kc_a) = pb0;
    *(float4*)(Bs + (1 * 128 + r_a) * LDK + kc_a) = pb1;
    *(float4*)(Bs + (2 * 128 + r_a) * LDK + kc_a) = pb2;
    int kn = k0 + 32;
    if (kn < 384) {
      pb0 = *(const float4*)(p.B2 + (size_t)(0 * 128 + r_a) * 384 + kn + kc_a);
      pb1 = *(const float4*)(p.B2 + (size_t)(1 * 128 + r_a) * 384 + kn + kc_a);
      pb2 = *(const float4*)(p.B2 + (size_t)(2 * 128 + r_a) * 384 + kn + kc_a);
    }
    asm volatile("s_waitcnt lgkmcnt(0)" ::: "memory");
    __builtin_amdgcn_sched_barrier(0);
    __builtin_amdgcn_s_barrier();
#pragma unroll
    for (int ks = 0; ks < 32; ks += 16) {
      int kloc = ks + lh * 8;
      bf16x8 a0 = *(const bf16x8*)(H + (rg * 64 + l31) * HLD + k0 + kloc);
      bf16x8 a1 = *(const bf16x8*)(H + (rg * 64 + 32 + l31) * HLD + k0 + kloc);
      bf16x8 b0 = *(const bf16x8*)(Bs + (cq * 96 + l31) * LDK + kloc);
      bf16x8 b1 = *(const bf16x8*)(Bs + (cq * 96 + 32 + l31) * LDK + kloc);
      bf16x8 b2 = *(const bf16x8*)(Bs + (cq * 96 + 64 + l31) * LDK + kloc);
      acc[0][0] = __builtin_amdgcn_mfma_f32_32x32x16_bf16(a0, b0, acc[0][0], 0, 0, 0);
      acc[1][0] = __builtin_amdgcn_mfma_f32_32x32x16_bf16(a1, b0, acc[1][0], 0, 0, 0);
      acc[0][1] = __builtin_amdgcn_mfma_f32_32x32x16_bf16(a0, b1, acc[0][1], 0, 0, 0);
      acc[1][1] = __builtin_amdgcn_mfma_f32_32x32x16_bf16(a1, b1, acc[1][1], 0, 0, 0);
      acc[0][2] = __builtin_amdgcn_mfma_f32_32x32x16_bf16(a0, b2, acc[0][2], 0, 0, 0);
      acc[1][2] = __builtin_amdgcn_mfma_f32_32x32x16_bf16(a1, b2, acc[1][2], 0, 0, 0);
    }
    __builtin_amdgcn_s_barrier();
  }
  // ---- per-row norm partials (this wave's 96-col quarter) ----
#pragma unroll
  for (int rf = 0; rf < 2; ++rf)
#pragma unroll
    for (int reg = 0; reg < 16; ++reg) {
      float s = acc[rf][0][reg] * acc[rf][0][reg] + acc[rf][1][reg] * acc[rf][1][reg] +
                acc[rf][2][reg] * acc[rf][2][reg];
      s += __shfl_xor(s, 1, 64);
      s += __shfl_xor(s, 2, 64);
      s += __shfl_xor(s, 4, 64);
      s += __shfl_xor(s, 8, 64);
      s += __shfl_xor(s, 16, 64);
      if (l31 == 0)
        nsum[rg * 64 + rf * 32 + (reg & 3) + 8 * (reg >> 2) + 4 * lh][cq] = s;
    }
  __syncthreads();
  // ---- expmap0 + proj + store ----
  const float maxn = 1.0f - 4e-3f;
#pragma unroll
  for (int rf = 0; rf < 2; ++rf)
#pragma unroll
    for (int reg = 0; reg < 16; ++reg) {
      int rl = rg * 64 + rf * 32 + (reg & 3) + 8 * (reg >> 2) + 4 * lh;
      int rr = row0 + rl;
      if (rr >= p.M) continue;
      float s = nsum[rl][0] + nsum[rl][1] + nsum[rl][2] + nsum[rl][3];
      float n = fmaxf(sqrtf(s), 1e-15f);
      float th = tanhf(n);
      float fct = th / n;
      float n2 = fmaxf(th, 1e-15f);
      if (n2 > maxn) fct *= maxn / n2;
      float* base = (rr < p.split) ? (p.Cf + (size_t)rr * 384)
                                   : (p.Cf2 + (size_t)(rr - p.split) * 384);
#pragma unroll
      for (int f = 0; f < 3; ++f)
        base[cq * 96 + f * 32 + l31] = acc[rf][f][reg] * fct;
    }
}

// ---------------- global_add_pool over sorted batch, interleaved layout ----------

__global__ __launch_bounds__(768) void pool2_kernel(const short* __restrict__ NB,
                                                    const int* __restrict__ gptr,
                                                    short* __restrict__ GCb,
                                                    short* __restrict__ nbappend) {
  int g = blockIdx.x, t = threadIdx.x;  // t in [0,768)
  int s = gptr[g], e = gptr[g + 1];
  float acc = 0.0f;
  for (int i = s; i < e; ++i) acc += b2f(NB[(size_t)i * 768 + t]);
  short bv = f2b(acc);
  int l = t >> 8, rem = t & 255, b = rem >> 7, c = rem & 127;
  GCb[(size_t)g * 768 + b * 384 + l * 128 + c] = bv;
  nbappend[(size_t)g * 768 + t] = bv;
}

// ---------------- driver ----------------

extern "C" void kernel_launch(void* const* d_in, const int* in_sizes, int n_in,
                              void* d_out, int out_size, void* d_ws, size_t ws_size,
                              hipStream_t stream) {
  (void)in_sizes; (void)n_in; (void)out_size; (void)ws_size;
  const float* x   = (const float*)d_in[0];
  const float* x_s = (const float*)d_in[1];
  const int* src   = (const int*)d_in[2];
  const int* dst   = (const int*)d_in[3];
  const int* batch = (const int*)d_in[4];
  const float* Wf[3] = {(const float*)d_in[5], (const float*)d_in[6], (const float*)d_in[7]};
  const float* bf[3] = {(const float*)d_in[8], (const float*)d_in[9], (const float*)d_in[10]};
  const float* Wsb[3] = {(const float*)d_in[11], (const float*)d_in[12], (const float*)d_in[13]};
  const float* bs[3] = {(const float*)d_in[14], (const float*)d_in[15], (const float*)d_in[16]};
  const float* P1 = (const float*)d_in[17];
  const float* P2 = (const float*)d_in[18];
  const float* G1 = (const float*)d_in[19];
  const float* G2 = (const float*)d_in[20];
  float* out = (float*)d_out;

  char* w = (char*)d_ws;
  auto alloc = [&](size_t bytes) {
    char* p = w;
    w += (bytes + 255) & ~(size_t)255;
    return p;
  };
  short* Ab    = (short*)alloc((size_t)N_NODES * 256 * 2);   // logmap out, interleaved
  short* Xa    = (short*)alloc((size_t)N_NODES * 256 * 2);   // aggregated, interleaved
  short* NB    = (short*)alloc((size_t)M_ALL * 768 * 2);     // [row][l][branch][128]
  int* cnt     = (int*)alloc((size_t)N_NODES * 4);
  int* row_ptr = (int*)alloc((size_t)(N_NODES + 1) * 4);
  int* cursor  = (int*)alloc((size_t)N_NODES * 4);
  float* dinv  = (float*)alloc((size_t)N_NODES * 4);
  int* col     = (int*)alloc((size_t)N_EDGES * 4);
  float* ew    = (float*)alloc((size_t)N_EDGES * 4);
  int* gptr    = (int*)alloc((size_t)(N_GRAPHS + 1) * 4);
  int* bsum    = (int*)alloc(256 * 4);
  short* GCb   = (short*)alloc((size_t)N_GRAPHS * 768 * 2);
  short* P1t   = (short*)alloc((size_t)EDIM * EDIM * 2);
  short* P2t   = (short*)alloc((size_t)EDIM * EDIM * 2);
  short* G1t   = (short*)alloc((size_t)768 * EDIM * 2);
  short* G2t   = (short*)alloc((size_t)EDIM * EDIM * 2);
  short* Wft[3], *Wst[3];
  for (int l = 0; l < 3; ++l) {
    Wft[l] = (short*)alloc((size_t)128 * 128 * 2);
    Wst[l] = (short*)alloc((size_t)128 * 128 * 2);
  }

  // ---- weight convert (independent of graph) ----
  {
    WcArgs wa;
    wa.seg[0] = {P1, P1t, EDIM, EDIM};
    wa.seg[1] = {P2, P2t, EDIM, EDIM};
    wa.seg[2] = {G1, G1t, 768, EDIM};
    wa.seg[3] = {G2, G2t, EDIM, EDIM};
    for (int l = 0; l < 3; ++l) {
      wa.seg[4 + l] = {Wf[l], Wft[l], 128, 128};
      wa.seg[7 + l] = {Wsb[l], Wst[l], 128, 128};
    }
    wconv_all_kernel<<<dim3((768 * EDIM + 255) / 256, 10), 256, 0, stream>>>(wa);
  }

  // ---- graph structure: 5 launches ----
  init_kernel<<<SCAN_NB, SCAN_BS, 0, stream>>>(batch, cnt, gptr);
  hist_kernel<<<(N_EDGES + 255) / 256, 256, 0, stream>>>(dst, cnt);
  scan1_kernel<<<SCAN_NB, SCAN_BS, 0, stream>>>(cnt, row_ptr, bsum);
  scan3_kernel<<<SCAN_NB, SCAN_BS, 0, stream>>>(cnt, bsum, row_ptr, cursor, dinv);
  scatter_kernel<<<(N_EDGES + 255) / 256, 256, 0, stream>>>(src, dst, dinv, cursor, col, ew);

  const size_t OUT0 = 0;
  const size_t OUT1 = (size_t)N_GRAPHS * EDIM;
  const size_t OUT2 = OUT1 + (size_t)N_GRAPHS * EDIM;
  const size_t OUT3 = OUT2 + (size_t)N_NODES * EDIM;

  const int gx_layer = (N_NODES + 127) / 128;   // 391
  const int gx_mfma  = (M_ALL + 127) / 128;     // 395
  const int gx_agg   = (N_NODES + 3) / 4;       // 12500

  // ---- logmap both branches -> interleaved Ab ----
  logmap2_kernel<<<(2 * N_NODES + 3) / 4, 256, 0, stream>>>(x, x_s, Ab);

  // ---- 3 GCN layers, both branches per launch ----
  const short* cur = Ab;
  int clda = 256;
  for (int l = 0; l < 3; ++l) {
    agg2_kernel<<<gx_agg, 256, 0, stream>>>(cur, clda, dinv, row_ptr, col, ew, Xa);
    GemmZArgs ga = {};
    ga.A[0] = Xa;        ga.A[1] = Xa + 128;
    ga.Bt[0] = Wft[l];   ga.Bt[1] = Wst[l];
    ga.bias[0] = bf[l];  ga.bias[1] = bs[l];
    ga.Cb[0] = NB + l * 256;        ga.Cb[1] = NB + l * 256 + 128;
    ga.lda = 256; ga.ldc = 768; ga.M = N_NODES; ga.Nc = 128; ga.K = 128;
    ga.kexp = 0; ga.do_relu = 1;
    mfma_gemmz_kernel<<<dim3(gx_layer, 1, 2), 256, 0, stream>>>(ga);
    cur = NB + l * 256;
    clda = 768;
  }

  // ---- pool (both branches) + append pooled rows to NB ----
  pool2_kernel<<<N_GRAPHS, 768, 0, stream>>>(NB, gptr, GCb, NB + (size_t)N_NODES * 768);

  // ---- all MLP heads in ONE dispatch: z=0/1 node+graph heads, tail-x = g head ----
  {
    const int gx_g = (N_GRAPHS + 127) / 128;  // 4
    Mlp2Args h = {};
    h.p[0] = {NB,       P1t, P2t, out + OUT2,
              out + OUT1, 768, M_ALL, EDIM, 1, N_NODES};
    h.p[1] = {NB + 128, P1t, P2t, out + OUT3 + (size_t)N_GRAPHS * EDIM,
              out + OUT3, 768, M_ALL, EDIM, 1, N_NODES};
    h.p[2] = {GCb, G1t, G2t, out + OUT0, out + OUT0, 768, N_GRAPHS, 768, 0, 1 << 30};
    h.gx_h = gx_mfma;
    mlp2_kernel<<<dim3(gx_mfma + gx_g, 1, 2), 512, 0, stream>>>(h);
  }
}